// Round 5
// baseline (53.870 us; speedup 1.0000x reference)
//
#include <hip/hip_runtime.h>
#include <hip/hip_bf16.h>
#include <math.h>

typedef __bf16 bf16;
typedef __bf16 bf16x4 __attribute__((ext_vector_type(4)));
typedef __bf16 bf16x8 __attribute__((ext_vector_type(8)));
typedef float  f32x4  __attribute__((ext_vector_type(4)));

static constexpr int kTokens = 32768;   // B*S = 8*4096
static constexpr int kH   = 768;
static constexpr int kC   = 64;
static constexpr int kLDW = kH + 8;     // 776 bf16 -> row stride 1552 B == 16 B mod 128: balanced banks

// ---------- prep: Wt[n][k] = W_e1^T (rows 0..63), row 64 = w_sc; b_sc scalar ----------
__global__ void prep_kernel(const float* __restrict__ W_ct,
                            const float* __restrict__ b_ct,
                            const float* __restrict__ W_cd,
                            const float* __restrict__ b_cd,
                            const float* __restrict__ W_e1,
                            bf16* __restrict__ Wt,
                            float* __restrict__ bsc) {
    int gidx = blockIdx.x * blockDim.x + threadIdx.x;
    if (gidx < kH * kC) {                       // transpose-copy, coalesced reads
        int k = gidx >> 6;
        int n = gidx & 63;
        Wt[(size_t)n * kH + k] = (bf16)W_e1[gidx];
    } else if (gidx < kH * kC + kH) {           // w_sc = W_ct @ W_cd
        int k = gidx - kH * kC;
        float s = 0.f;
        #pragma unroll 8
        for (int c = 0; c < kC; ++c) s += W_ct[k * kC + c] * W_cd[c];
        Wt[(size_t)kC * kH + k] = (bf16)s;
    } else if (gidx == kH * kC + kH) {
        float s = b_cd[0];
        for (int c = 0; c < kC; ++c) s += b_ct[c] * W_cd[c];
        bsc[0] = s;                             // b_sc = b_ct @ W_cd + b_cd
    }
}

// ---- cooperative A-tile staging: 16 rows x 768 f32 -> bf16, 3072 float4 chunks ----
__device__ __forceinline__ void stage_issue(float4 (&st)[10], const float* __restrict__ base,
                                            int tid) {
    #pragma unroll
    for (int j = 0; j < 10; ++j) {
        if (j < 9 || tid < 192) {
            int c   = tid + j * 320;
            int row = c / 192;                  // 192 float4 per row
            int col = (c - row * 192) * 4;
            st[j] = *reinterpret_cast<const float4*>(base + (size_t)row * kH + col);
        }
    }
}
__device__ __forceinline__ void stage_write(const float4 (&st)[10], bf16 (*buf)[kLDW],
                                            int tid) {
    #pragma unroll
    for (int j = 0; j < 10; ++j) {
        if (j < 9 || tid < 192) {
            int c   = tid + j * 320;
            int row = c / 192;
            int col = (c - row * 192) * 4;
            bf16x4 w;
            w[0] = (bf16)st[j].x; w[1] = (bf16)st[j].y;
            w[2] = (bf16)st[j].z; w[3] = (bf16)st[j].w;
            *reinterpret_cast<bf16x4*>(&buf[row][col]) = w;
        }
    }
}

// ---------- main: B in VGPRs (per-wave n-group), A double-buffered in LDS ----------
// Block = 5 waves (ng 0..3 = e1 cols, ng 4 = sc col), 4 token-tiles per block.
// Inner loop per tile: 24 x { ds_read_b128 ; MFMA } — no global ops, no B traffic.
__global__ __launch_bounds__(320, 3) void incong_main(
    const float* __restrict__ hs,      // [kTokens][kH] f32
    const bf16*  __restrict__ Wt,      // [>=65][kH] bf16
    const float* __restrict__ bsc_p,
    const float* __restrict__ b_e1,
    const float* __restrict__ W_e2,
    const float* __restrict__ b_e2,
    float* __restrict__ out)           // [3][kTokens]
{
    __shared__ bf16  lds_a[2][16][kLDW];    // 2 x 24.8 KB token tiles
    __shared__ float red[2][4][16];         // per-tile ev partials (ng x token)

    const int tid  = threadIdx.x;
    const int lane = tid & 63;
    const int ng   = tid >> 6;         // 0..4 column group
    const int r16  = lane & 15;
    const int kg   = lane >> 4;        // 0..3

    // ---- B fragments into registers (24 x bf16x8 = 96 VGPR), L2-resident read ----
    const int   bcol = min(ng * 16 + r16, 64);   // ng4: all lanes clamp to sc col
    const bf16* bp   = Wt + (size_t)bcol * kH + kg * 8;
    bf16x8 breg[24];
    #pragma unroll
    for (int i = 0; i < 24; ++i)
        breg[i] = *reinterpret_cast<const bf16x8*>(bp + i * 32);

    const int   tok0 = blockIdx.x * 64;
    const float be2  = b_e2[0];
    const float bsc  = bsc_p[0];
    float be = 0.f, we = 0.f;
    if (ng < 4) { be = b_e1[ng * 16 + r16]; we = W_e2[ng * 16 + r16]; }

    // ---- prologue: stage tile 0 ----
    {
        float4 st[10];
        stage_issue(st, hs + (size_t)tok0 * kH, tid);
        stage_write(st, lds_a[0], tid);
    }
    __syncthreads();

    #pragma unroll
    for (int t = 0; t < 4; ++t) {
        const int p     = t & 1;
        const int mytok = tok0 + t * 16;

        float4 st[10];
        if (t < 3) stage_issue(st, hs + (size_t)(mytok + 16) * kH, tid);  // T14 issue-early

        f32x4 acc = (f32x4){0.f, 0.f, 0.f, 0.f};
        const bf16* la = &lds_a[p][r16][kg * 8];
        #pragma unroll
        for (int i = 0; i < 24; ++i) {
            const bf16x8 af = *reinterpret_cast<const bf16x8*>(la + i * 32);
            acc = __builtin_amdgcn_mfma_f32_16x16x32_bf16(af, breg[i], acc, 0, 0, 0);
        }

        // D layout: col = r16 (this wave's cols), row(token) = kg*4 + reg
        if (ng < 4) {
            float p0 = fmaxf(acc[0] + be, 0.f) * we;
            float p1 = fmaxf(acc[1] + be, 0.f) * we;
            float p2 = fmaxf(acc[2] + be, 0.f) * we;
            float p3 = fmaxf(acc[3] + be, 0.f) * we;
            #pragma unroll
            for (int m = 1; m < 16; m <<= 1) {
                p0 += __shfl_xor(p0, m);
                p1 += __shfl_xor(p1, m);
                p2 += __shfl_xor(p2, m);
                p3 += __shfl_xor(p3, m);
            }
            if (r16 == 0) {
                red[p][ng][kg * 4 + 0] = p0;
                red[p][ng][kg * 4 + 1] = p1;
                red[p][ng][kg * 4 + 2] = p2;
                red[p][ng][kg * 4 + 3] = p3;
            }
        } else if (r16 == 0) {
            #pragma unroll
            for (int r = 0; r < 4; ++r) {
                const int tok = mytok + kg * 4 + r;
                out[tok]               = 1.f / (1.f + __expf(-(acc[r] + bsc)));
                out[2 * kTokens + tok] = 1.f / 4096.f;   // mean of softmax == 1/S
            }
        }

        if (t < 3) stage_write(st, lds_a[p ^ 1], tid);   // write next tile (other buffer)
        __syncthreads();                                  // stage done + red[p] visible

        if (ng == 4 && lane < 16) {                       // finalize ev for tile t
            const float s = red[p][0][lane] + red[p][1][lane]
                          + red[p][2][lane] + red[p][3][lane] + be2;
            out[kTokens + mytok + lane] = 1.f / (1.f + __expf(-s));
        }
    }
}

extern "C" void kernel_launch(void* const* d_in, const int* in_sizes, int n_in,
                              void* d_out, int out_size, void* d_ws, size_t ws_size,
                              hipStream_t stream) {
    const float* hs   = (const float*)d_in[0];
    // d_in[1] = attention_mask (all ones, unused by the reference math)
    const float* W_ct = (const float*)d_in[2];
    const float* b_ct = (const float*)d_in[3];
    const float* W_cd = (const float*)d_in[4];
    const float* b_cd = (const float*)d_in[5];
    const float* W_e1 = (const float*)d_in[6];
    const float* b_e1 = (const float*)d_in[7];
    const float* W_e2 = (const float*)d_in[8];
    const float* b_e2 = (const float*)d_in[9];
    // d_in[10..13] = W_q, b_q, W_k, b_k — unused (surprise is exactly 1/S)

    bf16*  Wt  = (bf16*)d_ws;
    float* bsc = (float*)((char*)d_ws + (size_t)80 * kH * sizeof(bf16));

    const int prep_total = kH * kC + kH + 1;    // 49921
    prep_kernel<<<(prep_total + 255) / 256, 256, 0, stream>>>(
        W_ct, b_ct, W_cd, b_cd, W_e1, Wt, bsc);

    incong_main<<<kTokens / 64, 320, 0, stream>>>(
        hs, Wt, bsc, b_e1, W_e2, b_e2, (float*)d_out);
}

// Round 6
// 28.806 us; speedup vs baseline: 1.8701x; 1.8701x over previous
//
#include <hip/hip_runtime.h>
#include <hip/hip_bf16.h>
#include <math.h>

typedef __bf16 bf16;
typedef __bf16 bf16x8 __attribute__((ext_vector_type(8)));
typedef float  f32x4  __attribute__((ext_vector_type(4)));

static constexpr int kTokens = 32768;   // B*S = 8*4096
static constexpr int kH   = 768;
static constexpr int kC   = 64;
static constexpr int kKH  = 384;        // K half staged per LDS fill
static constexpr int kLDW = kKH + 8;    // 392 bf16 -> 784 B row stride, balanced banks

// ---------- prep (all-coalesced): Wt[n][k]=W_e1^T, row 64 = w_sc = W_ct@W_cd ----------
// blocks 0..11: transpose one 64(k) x 64(n) tile of W_e1 via LDS
// blocks 12..23: w_sc for one 64-k chunk via LDS-resident dot
// block  24:     b_sc = b_ct@W_cd + b_cd
__global__ __launch_bounds__(256) void prep_kernel(
    const float* __restrict__ W_ct, const float* __restrict__ b_ct,
    const float* __restrict__ W_cd, const float* __restrict__ b_cd,
    const float* __restrict__ W_e1, bf16* __restrict__ Wt,
    float* __restrict__ bsc) {
    __shared__ float t[64][65];
    const int tid = threadIdx.x;
    const int b   = blockIdx.x;
    if (b < 12) {
        const int k0 = b * 64;
        #pragma unroll
        for (int i = 0; i < 16; ++i) {
            int idx = tid + i * 256;
            int k = idx >> 6, n = idx & 63;
            t[k][n] = W_e1[(size_t)(k0 + k) * kC + n];     // coalesced 256B reads
        }
        __syncthreads();
        #pragma unroll
        for (int i = 0; i < 16; ++i) {
            int idx = tid + i * 256;
            int n = idx >> 6, k = idx & 63;
            Wt[(size_t)n * kH + k0 + k] = (bf16)t[k][n];   // coalesced 128B writes
        }
    } else if (b < 24) {
        const int k0 = (b - 12) * 64;
        #pragma unroll
        for (int i = 0; i < 16; ++i) {
            int idx = tid + i * 256;
            int k = idx >> 6, c = idx & 63;
            t[k][c] = W_ct[(size_t)(k0 + k) * kC + c];     // coalesced
        }
        __syncthreads();
        if (tid < 64) {
            float s = 0.f;
            #pragma unroll
            for (int c = 0; c < kC; ++c) s += t[tid][c] * W_cd[c];
            Wt[(size_t)kC * kH + k0 + tid] = (bf16)s;      // w_sc row
        }
    } else {
        if (tid < 64) {
            float v = b_ct[tid] * W_cd[tid];
            #pragma unroll
            for (int m = 1; m < 64; m <<= 1) v += __shfl_xor(v, m);
            if (tid == 0) bsc[0] = v + b_cd[0];
        }
    }
}

// ---- stage one K-half of B (65 rows x 384 bf16) into LDS, cooperative 512 thr ----
__device__ __forceinline__ void stage_half(const bf16* __restrict__ Wt, int h,
                                           bf16 (*lds_w)[kLDW], int tid) {
    // 65 * 48 = 3120 bf16x8 chunks
    #pragma unroll
    for (int j = 0; j < 7; ++j) {
        int c = tid + j * 512;
        if (j < 6 || c < 3120) {
            int row = c / 48;
            int col = (c - row * 48) * 8;
            *reinterpret_cast<bf16x8*>(&lds_w[row][col]) =
                *reinterpret_cast<const bf16x8*>(&Wt[(size_t)row * kH + h * kKH + col]);
        }
    }
}

// ---------- main: (32768 x 768) @ (768 x 80) bf16 MFMA ----------
// B LDS halved via 2-stage K reuse of one 51 KB buffer -> 2-3 blocks/CU resident.
// 8 waves x 16-token full-K tiles; A global->reg->cvt->MFMA; 3 barriers per block.
__global__ __launch_bounds__(512, 4) void incong_main(
    const float* __restrict__ hs,      // [kTokens][kH] f32
    const bf16*  __restrict__ Wt,      // [65][kH] bf16
    const float* __restrict__ bsc_p,
    const float* __restrict__ b_e1,
    const float* __restrict__ W_e2,
    const float* __restrict__ b_e2,
    float* __restrict__ out)           // [3][kTokens]
{
    __shared__ bf16 lds_w[65][kLDW];   // 50.96 KB

    const int tid  = threadIdx.x;
    const int lane = tid & 63;
    const int wv   = tid >> 6;         // 0..7: tile within block
    const int r16  = lane & 15;
    const int kg   = lane >> 4;        // 0..3

    const int tok0 = (blockIdx.x * 8 + wv) * 16;
    const float* ap = hs + (size_t)(tok0 + r16) * kH + kg * 8;

    f32x4 acc[5];
    #pragma unroll
    for (int n = 0; n < 5; ++n) acc[n] = (f32x4){0.f, 0.f, 0.f, 0.f};

    const bf16* lp  = &lds_w[r16][kg * 8];   // rows n*16+r16, n=0..3
    const bf16* lp4 = &lds_w[64][kg * 8];    // sc row: uniform -> LDS broadcast

    #pragma unroll
    for (int h = 0; h < 2; ++h) {
        if (h) __syncthreads();                    // all waves done reading half 0
        stage_half(Wt, h, lds_w, tid);
        __syncthreads();

        const float* aph = ap + h * kKH;
        #pragma unroll
        for (int ks = 0; ks < kKH; ks += 64) {     // 6 bodies x 2 MFMA-steps
            const float4 a0 = *reinterpret_cast<const float4*>(aph + ks);
            const float4 a1 = *reinterpret_cast<const float4*>(aph + ks + 4);
            const float4 a2 = *reinterpret_cast<const float4*>(aph + ks + 32);
            const float4 a3 = *reinterpret_cast<const float4*>(aph + ks + 36);
            bf16x8 af;
            af[0] = (bf16)a0.x; af[1] = (bf16)a0.y; af[2] = (bf16)a0.z; af[3] = (bf16)a0.w;
            af[4] = (bf16)a1.x; af[5] = (bf16)a1.y; af[6] = (bf16)a1.z; af[7] = (bf16)a1.w;
            #pragma unroll
            for (int n = 0; n < 4; ++n) {
                const bf16x8 bfr = *reinterpret_cast<const bf16x8*>(
                    lp + (size_t)(n * 16) * kLDW + ks);
                acc[n] = __builtin_amdgcn_mfma_f32_16x16x32_bf16(af, bfr, acc[n], 0, 0, 0);
            }
            {
                const bf16x8 b4 = *reinterpret_cast<const bf16x8*>(lp4 + ks);
                acc[4] = __builtin_amdgcn_mfma_f32_16x16x32_bf16(af, b4, acc[4], 0, 0, 0);
            }
            bf16x8 ag;
            ag[0] = (bf16)a2.x; ag[1] = (bf16)a2.y; ag[2] = (bf16)a2.z; ag[3] = (bf16)a2.w;
            ag[4] = (bf16)a3.x; ag[5] = (bf16)a3.y; ag[6] = (bf16)a3.z; ag[7] = (bf16)a3.w;
            #pragma unroll
            for (int n = 0; n < 4; ++n) {
                const bf16x8 bfr = *reinterpret_cast<const bf16x8*>(
                    lp + (size_t)(n * 16) * kLDW + ks + 32);
                acc[n] = __builtin_amdgcn_mfma_f32_16x16x32_bf16(ag, bfr, acc[n], 0, 0, 0);
            }
            {
                const bf16x8 b4 = *reinterpret_cast<const bf16x8*>(lp4 + ks + 32);
                acc[4] = __builtin_amdgcn_mfma_f32_16x16x32_bf16(ag, b4, acc[4], 0, 0, 0);
            }
        }
    }

    // ---- epilogue (per wave; D layout: col = lane&15, row = kg*4 + reg) ----
    float part[4] = {0.f, 0.f, 0.f, 0.f};
    #pragma unroll
    for (int n = 0; n < 4; ++n) {
        const int cidx = n * 16 + r16;
        const float be = b_e1[cidx];
        const float we = W_e2[cidx];
        #pragma unroll
        for (int r = 0; r < 4; ++r)
            part[r] += fmaxf(acc[n][r] + be, 0.f) * we;
    }
    #pragma unroll
    for (int m = 1; m < 16; m <<= 1) {
        #pragma unroll
        for (int r = 0; r < 4; ++r) part[r] += __shfl_xor(part[r], m);
    }
    if (r16 == 0) {
        const float bsc = bsc_p[0];
        const float be2 = b_e2[0];
        #pragma unroll
        for (int r = 0; r < 4; ++r) {
            const int tok = tok0 + kg * 4 + r;
            const float sc = acc[4][r] + bsc;          // sc column accumulator
            out[tok]               = 1.f / (1.f + __expf(-sc));
            out[kTokens + tok]     = 1.f / (1.f + __expf(-(part[r] + be2)));
            out[2 * kTokens + tok] = 1.f / 4096.f;     // mean of softmax == 1/S
        }
    }
}

extern "C" void kernel_launch(void* const* d_in, const int* in_sizes, int n_in,
                              void* d_out, int out_size, void* d_ws, size_t ws_size,
                              hipStream_t stream) {
    const float* hs   = (const float*)d_in[0];
    // d_in[1] = attention_mask (all ones, unused by the reference math)
    const float* W_ct = (const float*)d_in[2];
    const float* b_ct = (const float*)d_in[3];
    const float* W_cd = (const float*)d_in[4];
    const float* b_cd = (const float*)d_in[5];
    const float* W_e1 = (const float*)d_in[6];
    const float* b_e1 = (const float*)d_in[7];
    const float* W_e2 = (const float*)d_in[8];
    const float* b_e2 = (const float*)d_in[9];
    // d_in[10..13] = W_q, b_q, W_k, b_k — unused (surprise is exactly 1/S)

    bf16*  Wt  = (bf16*)d_ws;
    float* bsc = (float*)((char*)d_ws + (size_t)80 * kH * sizeof(bf16));

    prep_kernel<<<25, 256, 0, stream>>>(W_ct, b_ct, W_cd, b_cd, W_e1, Wt, bsc);

    incong_main<<<kTokens / (16 * 8), 512, 0, stream>>>(
        hs, Wt, bsc, b_e1, W_e2, b_e2, (float*)d_out);
}

// Round 7
// 27.734 us; speedup vs baseline: 1.9424x; 1.0386x over previous
//
#include <hip/hip_runtime.h>
#include <hip/hip_bf16.h>
#include <math.h>

typedef __bf16 bf16;
typedef __bf16 bf16x8 __attribute__((ext_vector_type(8)));
typedef float  f32x4  __attribute__((ext_vector_type(4)));

static constexpr int kTokens = 32768;   // B*S = 8*4096
static constexpr int kH   = 768;
static constexpr int kC   = 64;
static constexpr int kCK  = 64;         // K-chunk (A rows = 256 B, power of 2)
static constexpr int kNQ  = kH / kCK;   // 12 chunks
static constexpr int kTB  = 64;         // tokens per block (4 waves x 16)
static constexpr int kBW  = 72;         // B lds row stride (144 B == 16 mod 128: balanced)

// ---------- prep (all-coalesced): Wt[n][k]=W_e1^T, row 64 = w_sc = W_ct@W_cd ----------
__global__ __launch_bounds__(256) void prep_kernel(
    const float* __restrict__ W_ct, const float* __restrict__ b_ct,
    const float* __restrict__ W_cd, const float* __restrict__ b_cd,
    const float* __restrict__ W_e1, bf16* __restrict__ Wt,
    float* __restrict__ bsc) {
    __shared__ float t[64][65];
    const int tid = threadIdx.x;
    const int b   = blockIdx.x;
    if (b < 12) {
        const int k0 = b * 64;
        #pragma unroll
        for (int i = 0; i < 16; ++i) {
            int idx = tid + i * 256;
            int k = idx >> 6, n = idx & 63;
            t[k][n] = W_e1[(size_t)(k0 + k) * kC + n];
        }
        __syncthreads();
        #pragma unroll
        for (int i = 0; i < 16; ++i) {
            int idx = tid + i * 256;
            int n = idx >> 6, k = idx & 63;
            Wt[(size_t)n * kH + k0 + k] = (bf16)t[k][n];
        }
    } else if (b < 24) {
        const int k0 = (b - 12) * 64;
        #pragma unroll
        for (int i = 0; i < 16; ++i) {
            int idx = tid + i * 256;
            int k = idx >> 6, c = idx & 63;
            t[k][c] = W_ct[(size_t)(k0 + k) * kC + c];
        }
        __syncthreads();
        if (tid < 64) {
            float s = 0.f;
            #pragma unroll
            for (int c = 0; c < kC; ++c) s += t[tid][c] * W_cd[c];
            Wt[(size_t)kC * kH + k0 + tid] = (bf16)s;
        }
    } else {
        if (tid < 64) {
            float v = b_ct[tid] * W_cd[tid];
            #pragma unroll
            for (int m = 1; m < 64; m <<= 1) v += __shfl_xor(v, m);
            if (tid == 0) bsc[0] = v + b_cd[0];
        }
    }
}

// ---- issue one A-chunk (64 rows x 256 B) via global_load_lds, src pre-swizzled ----
// LDS dest is linear (wave-uniform base + lane*16); element (row,k) of the chunk ends
// up at byte (row*256) + ((k*4) ^ ((row&7)<<4)); readers apply the same XOR.
__device__ __forceinline__ void issue_a(const float* __restrict__ hs_blk, int q,
                                        float* __restrict__ buf, int wv, int lane) {
    #pragma unroll
    for (int r = 0; r < 4; ++r) {
        const int span   = wv * 4 + r;            // 0..15, 4 rows (1 KB) per issue
        const int absrow = span * 4 + (lane >> 4);
        const int colB   = (lane & 15) * 16;
        const int scol   = colB ^ ((absrow & 7) << 4);
        const char* src  = (const char*)(hs_blk + (size_t)absrow * kH + q * kCK) + scol;
        float* dst = buf + span * 256;            // wave-uniform
        __builtin_amdgcn_global_load_lds(
            (const __attribute__((address_space(1))) void*)src,
            (__attribute__((address_space(3))) void*)dst, 16, 0, 0);
    }
}

// ---------- main: (32768 x 768) @ (768 x 65) bf16 MFMA ----------
// A: f32 direct-to-LDS (global_load_lds, XOR-swizzled, double-buffered chunks).
// B: 65x64 bf16 chunk re-staged per K-chunk (L2-resident). Raw barriers + counted
// vmcnt keep the next A-chunk in flight across the barrier (no __syncthreads drain).
__global__ __launch_bounds__(256, 3) void incong_main(
    const float* __restrict__ hs,      // [kTokens][kH] f32
    const bf16*  __restrict__ Wt,      // [65][kH] bf16
    const float* __restrict__ bsc_p,
    const float* __restrict__ b_e1,
    const float* __restrict__ W_e2,
    const float* __restrict__ b_e2,
    float* __restrict__ out)           // [3][kTokens]
{
    __shared__ float lds_a[2][kTB][kCK];   // 2 x 16 KB, rows 256 B, no pad (swizzled)
    __shared__ bf16  lds_w[65][kBW];       // 9.4 KB

    const int tid  = threadIdx.x;
    const int lane = tid & 63;
    const int wv   = tid >> 6;         // 0..3: 16-token tile within block
    const int r16  = lane & 15;
    const int kg   = lane >> 4;        // 0..3

    const int tok0 = blockIdx.x * kTB;
    const float* hs_blk = hs + (size_t)tok0 * kH;

    f32x4 acc[5];
    #pragma unroll
    for (int n = 0; n < 5; ++n) acc[n] = (f32x4){0.f, 0.f, 0.f, 0.f};

    const int      trow  = wv * 16 + r16;
    const unsigned sw    = (unsigned)((r16 & 7) << 4);
    const char*    ab0   = (const char*)&lds_a[0][trow][0];
    const char*    ab1   = (const char*)&lds_a[1][trow][0];

    issue_a(hs_blk, 0, &lds_a[0][0][0], wv, lane);     // prologue: A(0) in flight

    for (int q = 0; q < kNQ; ++q) {
        const int b = q & 1;
        // ---- stage B chunk q (loads then writes; compiler's vmcnt before the
        //      ds_write drains A(q) exactly, leaving A(q+1) outstanding) ----
        {
            const int c0 = tid, c1 = tid + 256;
            const int row0 = c0 >> 3, col0 = (c0 & 7) * 8;
            const int row1 = c1 >> 3, col1 = (c1 & 7) * 8;
            bf16x8 v0 = *reinterpret_cast<const bf16x8*>(&Wt[(size_t)row0 * kH + q * kCK + col0]);
            bf16x8 v1 = *reinterpret_cast<const bf16x8*>(&Wt[(size_t)row1 * kH + q * kCK + col1]);
            bf16x8 v2;
            if (tid < 8) v2 = *reinterpret_cast<const bf16x8*>(&Wt[(size_t)64 * kH + q * kCK + tid * 8]);
            if (q + 1 < kNQ) issue_a(hs_blk, q + 1, &lds_a[b ^ 1][0][0], wv, lane);
            *reinterpret_cast<bf16x8*>(&lds_w[row0][col0]) = v0;
            *reinterpret_cast<bf16x8*>(&lds_w[row1][col1]) = v1;
            if (tid < 8) *reinterpret_cast<bf16x8*>(&lds_w[64][tid * 8]) = v2;
        }
        asm volatile("s_waitcnt lgkmcnt(0)" ::: "memory");
        __builtin_amdgcn_s_barrier();
        asm volatile("" ::: "memory");

        // ---- compute chunk q: swizzled A reads + MFMA ----
        const char* abase = b ? ab1 : ab0;
        #pragma unroll
        for (int s = 0; s < 2; ++s) {
            const unsigned o = (unsigned)(s * 128 + kg * 32);
            const f32x4 a0 = *reinterpret_cast<const f32x4*>(abase + (o ^ sw));
            const f32x4 a1 = *reinterpret_cast<const f32x4*>(abase + ((o + 16u) ^ sw));
            bf16x8 af;
            af[0] = (bf16)a0[0]; af[1] = (bf16)a0[1]; af[2] = (bf16)a0[2]; af[3] = (bf16)a0[3];
            af[4] = (bf16)a1[0]; af[5] = (bf16)a1[1]; af[6] = (bf16)a1[2]; af[7] = (bf16)a1[3];
            #pragma unroll
            for (int n = 0; n < 4; ++n) {
                const bf16x8 bfr = *reinterpret_cast<const bf16x8*>(
                    &lds_w[n * 16 + r16][s * 32 + kg * 8]);
                acc[n] = __builtin_amdgcn_mfma_f32_16x16x32_bf16(af, bfr, acc[n], 0, 0, 0);
            }
            {
                const bf16x8 b4 = *reinterpret_cast<const bf16x8*>(&lds_w[64][s * 32 + kg * 8]);
                acc[4] = __builtin_amdgcn_mfma_f32_16x16x32_bf16(af, b4, acc[4], 0, 0, 0);
            }
        }
        asm volatile("" ::: "memory");
        __builtin_amdgcn_s_barrier();      // all waves done reading before next overwrite
    }

    // ---- epilogue (per wave; D layout: col = lane&15, row = kg*4 + reg) ----
    float part[4] = {0.f, 0.f, 0.f, 0.f};
    #pragma unroll
    for (int n = 0; n < 4; ++n) {
        const int cidx = n * 16 + r16;
        const float be = b_e1[cidx];
        const float we = W_e2[cidx];
        #pragma unroll
        for (int r = 0; r < 4; ++r)
            part[r] += fmaxf(acc[n][r] + be, 0.f) * we;
    }
    #pragma unroll
    for (int m = 1; m < 16; m <<= 1) {
        #pragma unroll
        for (int r = 0; r < 4; ++r) part[r] += __shfl_xor(part[r], m);
    }
    if (r16 == 0) {
        const float bsc = bsc_p[0];
        const float be2 = b_e2[0];
        #pragma unroll
        for (int r = 0; r < 4; ++r) {
            const int tok = tok0 + wv * 16 + kg * 4 + r;
            const float sc = acc[4][r] + bsc;          // sc column accumulator
            out[tok]               = 1.f / (1.f + __expf(-sc));
            out[kTokens + tok]     = 1.f / (1.f + __expf(-(part[r] + be2)));
            out[2 * kTokens + tok] = 1.f / 4096.f;     // mean of softmax == 1/S
        }
    }
}

extern "C" void kernel_launch(void* const* d_in, const int* in_sizes, int n_in,
                              void* d_out, int out_size, void* d_ws, size_t ws_size,
                              hipStream_t stream) {
    const float* hs   = (const float*)d_in[0];
    // d_in[1] = attention_mask (all ones, unused by the reference math)
    const float* W_ct = (const float*)d_in[2];
    const float* b_ct = (const float*)d_in[3];
    const float* W_cd = (const float*)d_in[4];
    const float* b_cd = (const float*)d_in[5];
    const float* W_e1 = (const float*)d_in[6];
    const float* b_e1 = (const float*)d_in[7];
    const float* W_e2 = (const float*)d_in[8];
    const float* b_e2 = (const float*)d_in[9];
    // d_in[10..13] = W_q, b_q, W_k, b_k — unused (surprise is exactly 1/S)

    bf16*  Wt  = (bf16*)d_ws;
    float* bsc = (float*)((char*)d_ws + (size_t)80 * kH * sizeof(bf16));

    prep_kernel<<<25, 256, 0, stream>>>(W_ct, b_ct, W_cd, b_cd, W_e1, Wt, bsc);

    incong_main<<<kTokens / kTB, 256, 0, stream>>>(
        hs, Wt, bsc, b_e1, W_e2, b_e2, (float*)d_out);
}